// Round 6
// baseline (385.080 us; speedup 1.0000x reference)
//
#include <hip/hip_runtime.h>
#include <stdint.h>

#define HW 16384
#define Bn 16
#define Ln 24
#define Dn 256
#define Qn 256
#define Cn 256

typedef __attribute__((ext_vector_type(8))) short short8;
typedef __attribute__((ext_vector_type(4))) float f32x4;

__device__ __forceinline__ unsigned short f2bf(float f) {
  unsigned u = __builtin_bit_cast(unsigned, f);
  u += 0x7FFFu + ((u >> 16) & 1u);
  return (unsigned short)(u >> 16);
}
__device__ __forceinline__ float bf2f(unsigned short s) {
  return __builtin_bit_cast(float, (unsigned)s << 16);
}

__device__ __forceinline__ void gl_lds16(const void* gsrc, void* lds) {
  __builtin_amdgcn_global_load_lds(
      (const __attribute__((address_space(1))) unsigned int*)gsrc,
      (__attribute__((address_space(3))) unsigned int*)lds, 16, 0, 0);
}

// ---------------- kernel 1: k[b,l,q] = w_src[b,l,:]·fck_w[q,:] + fck_b[q] ----
__global__ void k_keys(const float* __restrict__ wsrc, const float* __restrict__ fckw,
                       const float* __restrict__ fckb, float* __restrict__ kmat) {
  int b = blockIdx.x / Ln, l = blockIdx.x % Ln;
  __shared__ float row[Dn];
  row[threadIdx.x] = wsrc[(b * Ln + l) * Dn + threadIdx.x];
  __syncthreads();
  int q = threadIdx.x;
  const float* wq = fckw + q * Dn;
  float acc = fckb[q];
#pragma unroll 8
  for (int d = 0; d < Dn; ++d) acc += row[d] * wq[d];
  kmat[(b * Ln + l) * Qn + q] = acc;
}

// ---------------- kernel 2: scores/argmax/w_alloc/bias0 ----------------------
__global__ void k_alloc(const float* __restrict__ wsrc, const float* __restrict__ wtgt,
                        const float* __restrict__ conv0b, const float* __restrict__ kmat,
                        float* __restrict__ walloc, float* __restrict__ bias0) {
  int b = blockIdx.x;
  __shared__ float S[Ln][Dn];
  __shared__ float T[Ln][Dn];
  __shared__ double sc[Ln][Ln];
  __shared__ double cs[Ln];
  __shared__ int idx[Ln];
  int tid = threadIdx.x;
  for (int n = tid; n < Ln * Dn; n += 256) {
    S[n >> 8][n & 255] = wsrc[b * Ln * Dn + n];
    T[n >> 8][n & 255] = wtgt[b * Ln * Dn + n];
  }
  __syncthreads();
  for (int p = tid; p < Ln * Ln; p += 256) {
    int l = p / Ln, m = p % Ln;
    double a = 0.0;
    for (int d = 0; d < Dn; ++d) a += (double)S[l][d] * (double)T[m][d];
    sc[l][m] = a;
  }
  __syncthreads();
  if (tid < Ln) {
    double a = 0.0;
    for (int l = 0; l < Ln; ++l) a += sc[l][tid];
    cs[tid] = a;
  }
  __syncthreads();
  if (tid < Ln) {
    double best = -1e300; int bi = 0;
    for (int m = 0; m < Ln; ++m) {
      double v = cs[m] - sc[tid][m];
      if (v > best) { best = v; bi = m; }
    }
    idx[tid] = bi;
  }
  __syncthreads();
  for (int n = tid; n < Ln * Dn; n += 256) {
    int l = n >> 8, d = n & 255;
    walloc[b * Ln * Dn + n] = T[idx[l]][d];
  }
  if (tid < Ln) {
    float a = 0.f;
    const float* kr = kmat + (b * Ln + tid) * Qn;
    for (int q = 0; q < Qn; ++q) a += conv0b[q] * kr[q];
    bias0[b * Ln + tid] = a;
  }
}

// ---------------- kernel 3: M[b,l,c] and bg[b,l,e] ---------------------------
__global__ void k_mbg(const float* __restrict__ kmat, const float* __restrict__ conv0w,
                      const float* __restrict__ walloc, const float* __restrict__ fcw,
                      const float* __restrict__ fcb,
                      float* __restrict__ Mmat, float* __restrict__ bg) {
  int bid = blockIdx.x;
  __shared__ float row[Dn];
  if (bid < Bn * Ln) {
    int b = bid / Ln, l = bid % Ln;
    row[threadIdx.x] = kmat[(b * Ln + l) * Qn + threadIdx.x];
    __syncthreads();
    int c = threadIdx.x;
    float acc = 0.f;
    for (int q = 0; q < Qn; ++q) acc += row[q] * conv0w[q * Cn + c];
    Mmat[(b * Ln + l) * Cn + c] = acc;
  } else {
    int id = bid - Bn * Ln;
    int b = id / Ln, l = id % Ln;
    row[threadIdx.x] = walloc[(b * Ln + l) * Dn + threadIdx.x];
    __syncthreads();
    for (int it = 0; it < 2; ++it) {
      int e = it * 256 + threadIdx.x;
      const float* we = fcw + e * Dn;
      float acc = fcb[e];
      for (int d = 0; d < Dn; ++d) acc += row[d] * we[d];
      bg[(b * Ln + l) * (2 * Cn) + e] = acc;
    }
  }
}

// ---------------- kernel 4: G blob per (b,g): pre-swizzled image + bv --------
// R2-VALIDATED image. 128 rows x 512B (k=256 bf16). Row r: isb=(r>>4)&1,
// c_loc = (r>>5)*16 + (r&15). gamma rows isb=0 (bg col 256+c), beta isb=1.
// byte(r,k) = r*512 + (k*2 ^ ((r&7)<<4)).
__global__ void k_gbuild(const float* __restrict__ Mmat, const float* __restrict__ bg,
                         const float* __restrict__ bias0,
                         unsigned short* __restrict__ Gt, float* __restrict__ bv) {
  int g = blockIdx.x, b = blockIdx.y;
  __shared__ float Ms[Ln][Dn];
  __shared__ float Gb[Ln][128];
  __shared__ float B0[Ln];
  int tid = threadIdx.x;
  for (int n = tid; n < Ln * Dn; n += 256) Ms[n >> 8][n & 255] = Mmat[b * Ln * Dn + n];
  for (int n = tid; n < Ln * 128; n += 256) {
    int l = n >> 7, j = n & 127;
    int e = (j < 64) ? (Cn + g * 64 + j) : (g * 64 + (j - 64));
    Gb[l][j] = bg[(b * Ln + l) * (2 * Cn) + e];
  }
  if (tid < Ln) B0[tid] = bias0[b * Ln + tid];
  __syncthreads();
  char* base = (char*)Gt + (unsigned long)(b * 4 + g) * 65536;
  for (int r = 0; r < 128; ++r) {
    int isb = (r >> 4) & 1;
    int c_loc = (r >> 5) * 16 + (r & 15);
    int j = c_loc + isb * 64;
    float acc = 0.f;
#pragma unroll
    for (int l = 0; l < Ln; ++l) acc += Ms[l][tid] * Gb[l][j];
    unsigned off = (unsigned)((r * 512 + tid * 2) ^ ((r & 7) << 4));
    *(unsigned short*)(base + off) = f2bf(acc);
  }
  if (tid < 128) {
    float a = 0.f;
#pragma unroll
    for (int l = 0; l < Ln; ++l) a += B0[l] * Gb[l][tid];
    bv[b * 512 + g * 128 + tid] = a;  // 0..63 gamma-bias, 64..127 beta-bias
  }
}

// ---------------- kernel 5: transpose h -> hT (PLAIN [b][hw][c] bf16) + stats
// R1-VALIDATED verbatim.
__global__ void k_tr(const float* __restrict__ h, unsigned short* __restrict__ hT,
                     float* __restrict__ part) {
  int hwc = blockIdx.x;  // 64 chunks of 256 hw
  int cc  = blockIdx.y;  // 4 chunks of 64 c
  int b   = blockIdx.z;
  int tid = threadIdx.x;
  int w = tid >> 6, lane = tid & 63;
  __shared__ unsigned short tile[64 * 258];
  __shared__ float red[64 * 17 + 16];
  const int c0 = cc * 64, hw0 = hwc * 256;
  for (int i = 0; i < 16; ++i) {
    int cl = i * 4 + w;
    f32x4 v = *(const f32x4*)(h + ((unsigned long)(b * Cn + c0 + cl)) * HW + hw0 + lane * 4);
    unsigned lo = (unsigned)f2bf(v.x) | ((unsigned)f2bf(v.y) << 16);
    unsigned hi = (unsigned)f2bf(v.z) | ((unsigned)f2bf(v.w) << 16);
    unsigned* dst = (unsigned*)(tile + cl * 258 + lane * 4);
    dst[0] = lo; dst[1] = hi;
  }
  __syncthreads();
  int cp = tid & 31, sub = tid >> 5;
  float s0 = 0.f, s20 = 0.f, s1 = 0.f, s21 = 0.f;
  for (int i = 0; i < 32; ++i) {
    int hw = i * 8 + sub;
    unsigned short a0 = tile[(2 * cp) * 258 + hw];
    unsigned short a1 = tile[(2 * cp + 1) * 258 + hw];
    float f0 = bf2f(a0), f1 = bf2f(a1);
    s0 += f0; s20 += f0 * f0; s1 += f1; s21 += f1 * f1;
    unsigned pk = (unsigned)a0 | ((unsigned)a1 << 16);
    *(unsigned*)(hT + ((unsigned long)b * HW + hw0 + hw) * Cn + c0 + 2 * cp) = pk;
  }
  red[(2 * cp) * 17 + sub * 2]     = s0;
  red[(2 * cp) * 17 + sub * 2 + 1] = s20;
  red[(2 * cp + 1) * 17 + sub * 2]     = s1;
  red[(2 * cp + 1) * 17 + sub * 2 + 1] = s21;
  __syncthreads();
  if (tid < 64) {
    float a = 0.f, q = 0.f;
#pragma unroll
    for (int j = 0; j < 8; ++j) { a += red[tid * 17 + j * 2]; q += red[tid * 17 + j * 2 + 1]; }
    float* pp = part + (((unsigned long)(b * Cn + c0 + tid)) * 64 + hwc) * 2;
    pp[0] = a; pp[1] = q;
  }
}

// ---------------- kernel 6: finalize stats -> scale/shift --------------------
__global__ void k_fin(const float* __restrict__ part, const float* __restrict__ inw,
                      const float* __restrict__ inb, float* __restrict__ ss) {
  int id = blockIdx.x * 256 + threadIdx.x;  // 4096 = B*C
  int c = id & 255;
  float s = 0.f, s2 = 0.f;
  const float* pp = part + (unsigned long)id * 128;
  for (int j = 0; j < 64; ++j) { s += pp[2 * j]; s2 += pp[2 * j + 1]; }
  float mean = s * (1.0f / HW);
  float var = s2 * (1.0f / HW) - mean * mean;
  float rs = rsqrtf(var + 1e-5f);
  float scv = rs * inw[c];
  float sh = inb[c] - mean * scv;
  ss[id * 2] = scv; ss[id * 2 + 1] = sh;
}

// ---------------- kernel 7: persistent fused GEMM + epilogue -----------------
// 512 blocks (1/CU): block = (xcd-octant o, b, g). 8 n-tiles of 256 hw.
// A (64KB G image) staged once; B chunks (256hw x 64c', 32KB) double-buffered,
// counted vmcnt(4). ALL gl_lds: wave-uniform LDS dest, per-lane GLOBAL src
// (swizzle folded into src address). lgkmcnt(0)+sched_barrier guard before
// the read-release barrier. Epilogue h read from global f32.
__global__ __launch_bounds__(512, 1) void k_main(
    const float* __restrict__ h, const unsigned short* __restrict__ hT,
    const unsigned short* __restrict__ Gt,
    const float* __restrict__ bv, const float* __restrict__ ss,
    float* __restrict__ out) {
  int x = blockIdx.x;
  int o = x & 7, idx = x >> 3;
  int b = idx >> 2, g = idx & 3;
  int tid = threadIdx.x;
  int w = tid >> 6, lane = tid & 63;
  int mw = w >> 2, nw = w & 3;
  int lr = lane & 15, lg = lane >> 4;

  __shared__ __align__(16) unsigned char Ab[65536];
  __shared__ __align__(16) unsigned char Bb[2][32768];

  const char* Gblob = (const char*)Gt + (unsigned long)(b * 4 + g) * 65536;
  const char* hTb = (const char*)hT + (unsigned long)b * HW * 512;  // plain rows
  const float* hb = h + (unsigned long)b * Cn * HW;

  // stage A once: linear copy of pre-swizzled image (wave-uniform dest)
#pragma unroll
  for (int i = 0; i < 8; ++i)
    gl_lds16(Gblob + i * 8192 + w * 1024 + lane * 16, &Ab[i * 8192 + w * 1024]);

  // B chunk c2 = t*4+s: hw rows (o*8+t)*256..+256, channels s*64..+64.
  // LDS image swizzled: Bb[row*128+cb] = hTplain[row][s*128 + (cb^((row&7)<<4))]
#define STAGE_B(c2, buf_)                                                        \
  {                                                                              \
    int s2_ = (c2) & 3, t2_ = (c2) >> 2;                                         \
    const char* base_ = hTb + (unsigned long)((o * 8 + t2_) * 256) * 512 + s2_ * 128; \
    _Pragma("unroll")                                                            \
    for (int l_ = 0; l_ < 4; ++l_) {                                             \
      int rowl_ = l_ * 64 + w * 8 + (lane >> 3);                                 \
      int bir_ = ((lane & 7) * 16) ^ ((rowl_ & 7) << 4);                         \
      gl_lds16(base_ + (unsigned long)rowl_ * 512 + bir_,                        \
               &Bb[buf_][l_ * 8192 + w * 1024]);                                 \
    }                                                                            \
  }

  STAGE_B(0, 0);
  STAGE_B(1, 1);
  asm volatile("s_waitcnt vmcnt(4)" ::: "memory");  // A + chunk0 done
  __builtin_amdgcn_s_barrier();
  __builtin_amdgcn_sched_barrier(0);

  f32x4 acc[4][4];
#pragma unroll
  for (int mf = 0; mf < 4; ++mf)
#pragma unroll
    for (int nf = 0; nf < 4; ++nf) acc[mf][nf] = (f32x4){0.f, 0.f, 0.f, 0.f};

  const float* ssb = ss + b * Cn * 2;
  const float* bvb = bv + b * 512 + g * 128;

  for (int t = 0; t < 8; ++t) {
#pragma unroll
    for (int s = 0; s < 4; ++s) {
      int ch = t * 4 + s;
      int buf = ch & 1;
      const unsigned char* Bcur = &Bb[buf][0];

#pragma unroll
      for (int kk = 0; kk < 2; ++kk) {
        short8 afr[4], bfr[4];
#pragma unroll
        for (int mf = 0; mf < 4; ++mf) {
          int row = mw * 64 + mf * 16 + lr;
          afr[mf] = *(const short8*)(
              &Ab[row * 512 + ((s * 128 + kk * 64 + lg * 16) ^ ((row & 7) << 4))]);
        }
#pragma unroll
        for (int nf = 0; nf < 4; ++nf) {
          int row = nw * 64 + nf * 16 + lr;
          bfr[nf] = *(const short8*)(
              &Bcur[row * 128 + ((kk * 64 + lg * 16) ^ ((row & 7) << 4))]);
        }
#pragma unroll
        for (int mf = 0; mf < 4; ++mf)
#pragma unroll
          for (int nf = 0; nf < 4; ++nf)
            acc[mf][nf] = __builtin_amdgcn_mfma_f32_16x16x32_bf16(afr[mf], bfr[nf],
                                                                  acc[mf][nf], 0, 0, 0);
      }

      if (s == 3) {  // epilogue for tile t: h from GLOBAL f32
        int hwbase = (o * 8 + t) * 256 + nw * 64 + lr;
#pragma unroll
        for (int p = 0; p < 2; ++p)
#pragma unroll
          for (int r = 0; r < 4; ++r) {
            int c_loc = (mw * 2 + p) * 16 + lg * 4 + r;  // R2-image D mapping
            int cch = g * 64 + c_loc;
            float scv = ssb[cch * 2], sh = ssb[cch * 2 + 1];
            float bvg = bvb[c_loc], bvbt = bvb[64 + c_loc];
            const float* hrow = hb + (unsigned long)cch * HW + hwbase;
            float* orow = out + (unsigned long)(b * Cn + cch) * HW + hwbase;
#pragma unroll
            for (int nf = 0; nf < 4; ++nf) {
              float hn = hrow[nf * 16] * scv + sh;
              orow[nf * 16] = hn * (acc[2 * p][nf][r] + bvg) + (acc[2 * p + 1][nf][r] + bvbt);
            }
          }
#pragma unroll
        for (int mf = 0; mf < 4; ++mf)
#pragma unroll
          for (int nf = 0; nf < 4; ++nf) acc[mf][nf] = (f32x4){0.f, 0.f, 0.f, 0.f};
      }

      // guard: no pending LDS reads may cross into the DMA overwrite
      asm volatile("s_waitcnt lgkmcnt(0)" ::: "memory");
      __builtin_amdgcn_sched_barrier(0);
      __builtin_amdgcn_s_barrier();  // all waves done reading Bb[buf]
      if (ch + 2 < 32) {
        STAGE_B(ch + 2, buf);
        asm volatile("s_waitcnt vmcnt(4)" ::: "memory");  // chunk ch+1 complete
      } else {
        asm volatile("s_waitcnt vmcnt(0)" ::: "memory");
      }
      __builtin_amdgcn_s_barrier();  // chunk ch+1 visible to all waves
      __builtin_amdgcn_sched_barrier(0);
    }
  }
#undef STAGE_B
}

__global__ void k_sentinel(float* out) { out[0] = 12345.0f; }

// ---------------- launcher ---------------------------------------------------
extern "C" void kernel_launch(void* const* d_in, const int* in_sizes, int n_in,
                              void* d_out, int out_size, void* d_ws, size_t ws_size,
                              hipStream_t stream) {
  const float* wsrc   = (const float*)d_in[0];
  const float* wtgt   = (const float*)d_in[1];
  const float* h      = (const float*)d_in[2];
  const float* conv0w = (const float*)d_in[3];
  const float* conv0b = (const float*)d_in[4];
  const float* fckw   = (const float*)d_in[5];
  const float* fckb   = (const float*)d_in[6];
  const float* fcw    = (const float*)d_in[7];
  const float* fcb    = (const float*)d_in[8];
  const float* inw    = (const float*)d_in[9];
  const float* inb    = (const float*)d_in[10];
  float* out = (float*)d_out;
  char* ws = (char*)d_ws;

  const size_t NEED = 142542848ull;
  if (ws_size < NEED) {
    k_sentinel<<<1, 1, 0, stream>>>(out);
    return;
  }

  unsigned short* hT = (unsigned short*)(ws + 0);           // 134217728
  float* kmat   = (float*)(ws + 134217728);                 // 393216
  float* walloc = (float*)(ws + 134610944);                 // 393216
  float* bias0  = (float*)(ws + 135004160);                 // 2048
  float* bg     = (float*)(ws + 135006208);                 // 786432
  float* Mmat   = (float*)(ws + 135792640);                 // 393216
  unsigned short* Gt = (unsigned short*)(ws + 136185856);   // 4194304
  float* bv     = (float*)(ws + 140380160);                 // 32768
  float* part   = (float*)(ws + 140412928);                 // 2097152
  float* ss     = (float*)(ws + 142510080);                 // 32768

  dim3 gt(64, 4, Bn);
  k_tr<<<gt, 256, 0, stream>>>(h, hT, part);
  k_keys<<<Bn * Ln, 256, 0, stream>>>(wsrc, fckw, fckb, kmat);
  k_alloc<<<Bn, 256, 0, stream>>>(wsrc, wtgt, conv0b, kmat, walloc, bias0);
  k_mbg<<<2 * Bn * Ln, 256, 0, stream>>>(kmat, conv0w, walloc, fcw, fcb, Mmat, bg);
  dim3 gg(4, Bn);
  k_gbuild<<<gg, 256, 0, stream>>>(Mmat, bg, bias0, Gt, bv);
  k_fin<<<16, 256, 0, stream>>>(part, inw, inb, ss);
  k_main<<<512, 512, 0, stream>>>(h, hT, Gt, bv, ss, out);
}

// Round 7
// 348.852 us; speedup vs baseline: 1.1038x; 1.1038x over previous
//
#include <hip/hip_runtime.h>
#include <stdint.h>

#define HW 16384
#define Bn 16
#define Ln 24
#define Dn 256
#define Qn 256
#define Cn 256

typedef __attribute__((ext_vector_type(8))) short short8;
typedef __attribute__((ext_vector_type(4))) float f32x4;

__device__ __forceinline__ unsigned short f2bf(float f) {
  unsigned u = __builtin_bit_cast(unsigned, f);
  u += 0x7FFFu + ((u >> 16) & 1u);
  return (unsigned short)(u >> 16);
}
__device__ __forceinline__ float bf2f(unsigned short s) {
  return __builtin_bit_cast(float, (unsigned)s << 16);
}

__device__ __forceinline__ void gl_lds16(const void* gsrc, void* lds) {
  __builtin_amdgcn_global_load_lds(
      (const __attribute__((address_space(1))) unsigned int*)gsrc,
      (__attribute__((address_space(3))) unsigned int*)lds, 16, 0, 0);
}

// ---------------- kernel 1: k[b,l,q] = w_src[b,l,:]·fck_w[q,:] + fck_b[q] ----
__global__ void k_keys(const float* __restrict__ wsrc, const float* __restrict__ fckw,
                       const float* __restrict__ fckb, float* __restrict__ kmat) {
  int b = blockIdx.x / Ln, l = blockIdx.x % Ln;
  __shared__ float row[Dn];
  row[threadIdx.x] = wsrc[(b * Ln + l) * Dn + threadIdx.x];
  __syncthreads();
  int q = threadIdx.x;
  const float* wq = fckw + q * Dn;
  float acc = fckb[q];
#pragma unroll 8
  for (int d = 0; d < Dn; ++d) acc += row[d] * wq[d];
  kmat[(b * Ln + l) * Qn + q] = acc;
}

// ---------------- kernel 2: scores/argmax/w_alloc/bias0 ----------------------
__global__ void k_alloc(const float* __restrict__ wsrc, const float* __restrict__ wtgt,
                        const float* __restrict__ conv0b, const float* __restrict__ kmat,
                        float* __restrict__ walloc, float* __restrict__ bias0) {
  int b = blockIdx.x;
  __shared__ float S[Ln][Dn];
  __shared__ float T[Ln][Dn];
  __shared__ double sc[Ln][Ln];
  __shared__ double cs[Ln];
  __shared__ int idx[Ln];
  int tid = threadIdx.x;
  for (int n = tid; n < Ln * Dn; n += 256) {
    S[n >> 8][n & 255] = wsrc[b * Ln * Dn + n];
    T[n >> 8][n & 255] = wtgt[b * Ln * Dn + n];
  }
  __syncthreads();
  for (int p = tid; p < Ln * Ln; p += 256) {
    int l = p / Ln, m = p % Ln;
    double a = 0.0;
    for (int d = 0; d < Dn; ++d) a += (double)S[l][d] * (double)T[m][d];
    sc[l][m] = a;
  }
  __syncthreads();
  if (tid < Ln) {
    double a = 0.0;
    for (int l = 0; l < Ln; ++l) a += sc[l][tid];
    cs[tid] = a;
  }
  __syncthreads();
  if (tid < Ln) {
    double best = -1e300; int bi = 0;
    for (int m = 0; m < Ln; ++m) {
      double v = cs[m] - sc[tid][m];
      if (v > best) { best = v; bi = m; }
    }
    idx[tid] = bi;
  }
  __syncthreads();
  for (int n = tid; n < Ln * Dn; n += 256) {
    int l = n >> 8, d = n & 255;
    walloc[b * Ln * Dn + n] = T[idx[l]][d];
  }
  if (tid < Ln) {
    float a = 0.f;
    const float* kr = kmat + (b * Ln + tid) * Qn;
    for (int q = 0; q < Qn; ++q) a += conv0b[q] * kr[q];
    bias0[b * Ln + tid] = a;
  }
}

// ---------------- kernel 3: M[b,l,c] and bg[b,l,e] ---------------------------
__global__ void k_mbg(const float* __restrict__ kmat, const float* __restrict__ conv0w,
                      const float* __restrict__ walloc, const float* __restrict__ fcw,
                      const float* __restrict__ fcb,
                      float* __restrict__ Mmat, float* __restrict__ bg) {
  int bid = blockIdx.x;
  __shared__ float row[Dn];
  if (bid < Bn * Ln) {
    int b = bid / Ln, l = bid % Ln;
    row[threadIdx.x] = kmat[(b * Ln + l) * Qn + threadIdx.x];
    __syncthreads();
    int c = threadIdx.x;
    float acc = 0.f;
    for (int q = 0; q < Qn; ++q) acc += row[q] * conv0w[q * Cn + c];
    Mmat[(b * Ln + l) * Cn + c] = acc;
  } else {
    int id = bid - Bn * Ln;
    int b = id / Ln, l = id % Ln;
    row[threadIdx.x] = walloc[(b * Ln + l) * Dn + threadIdx.x];
    __syncthreads();
    for (int it = 0; it < 2; ++it) {
      int e = it * 256 + threadIdx.x;
      const float* we = fcw + e * Dn;
      float acc = fcb[e];
      for (int d = 0; d < Dn; ++d) acc += row[d] * we[d];
      bg[(b * Ln + l) * (2 * Cn) + e] = acc;
    }
  }
}

// ---------------- kernel 4: G blob per (b,g): pre-swizzled image + bv --------
// R2/R6-VALIDATED image. 128 rows x 512B (k=256 bf16). Row r: isb=(r>>4)&1,
// c_loc = (r>>5)*16 + (r&15). gamma rows isb=0 (bg col 256+c), beta isb=1.
// byte(r,k) = r*512 + (k*2 ^ ((r&7)<<4)).
__global__ void k_gbuild(const float* __restrict__ Mmat, const float* __restrict__ bg,
                         const float* __restrict__ bias0,
                         unsigned short* __restrict__ Gt, float* __restrict__ bv) {
  int g = blockIdx.x, b = blockIdx.y;
  __shared__ float Ms[Ln][Dn];
  __shared__ float Gb[Ln][128];
  __shared__ float B0[Ln];
  int tid = threadIdx.x;
  for (int n = tid; n < Ln * Dn; n += 256) Ms[n >> 8][n & 255] = Mmat[b * Ln * Dn + n];
  for (int n = tid; n < Ln * 128; n += 256) {
    int l = n >> 7, j = n & 127;
    int e = (j < 64) ? (Cn + g * 64 + j) : (g * 64 + (j - 64));
    Gb[l][j] = bg[(b * Ln + l) * (2 * Cn) + e];
  }
  if (tid < Ln) B0[tid] = bias0[b * Ln + tid];
  __syncthreads();
  char* base = (char*)Gt + (unsigned long)(b * 4 + g) * 65536;
  for (int r = 0; r < 128; ++r) {
    int isb = (r >> 4) & 1;
    int c_loc = (r >> 5) * 16 + (r & 15);
    int j = c_loc + isb * 64;
    float acc = 0.f;
#pragma unroll
    for (int l = 0; l < Ln; ++l) acc += Ms[l][tid] * Gb[l][j];
    unsigned off = (unsigned)((r * 512 + tid * 2) ^ ((r & 7) << 4));
    *(unsigned short*)(base + off) = f2bf(acc);
  }
  if (tid < 128) {
    float a = 0.f;
#pragma unroll
    for (int l = 0; l < Ln; ++l) a += B0[l] * Gb[l][tid];
    bv[b * 512 + g * 128 + tid] = a;  // 0..63 gamma-bias, 64..127 beta-bias
  }
}

// ---------------- kernel 5: transpose h -> hT (PLAIN [b][hw][c] bf16) + stats
// R1/R6-VALIDATED verbatim.
__global__ void k_tr(const float* __restrict__ h, unsigned short* __restrict__ hT,
                     float* __restrict__ part) {
  int hwc = blockIdx.x;  // 64 chunks of 256 hw
  int cc  = blockIdx.y;  // 4 chunks of 64 c
  int b   = blockIdx.z;
  int tid = threadIdx.x;
  int w = tid >> 6, lane = tid & 63;
  __shared__ unsigned short tile[64 * 258];
  __shared__ float red[64 * 17 + 16];
  const int c0 = cc * 64, hw0 = hwc * 256;
  for (int i = 0; i < 16; ++i) {
    int cl = i * 4 + w;
    f32x4 v = *(const f32x4*)(h + ((unsigned long)(b * Cn + c0 + cl)) * HW + hw0 + lane * 4);
    unsigned lo = (unsigned)f2bf(v.x) | ((unsigned)f2bf(v.y) << 16);
    unsigned hi = (unsigned)f2bf(v.z) | ((unsigned)f2bf(v.w) << 16);
    unsigned* dst = (unsigned*)(tile + cl * 258 + lane * 4);
    dst[0] = lo; dst[1] = hi;
  }
  __syncthreads();
  int cp = tid & 31, sub = tid >> 5;
  float s0 = 0.f, s20 = 0.f, s1 = 0.f, s21 = 0.f;
  for (int i = 0; i < 32; ++i) {
    int hw = i * 8 + sub;
    unsigned short a0 = tile[(2 * cp) * 258 + hw];
    unsigned short a1 = tile[(2 * cp + 1) * 258 + hw];
    float f0 = bf2f(a0), f1 = bf2f(a1);
    s0 += f0; s20 += f0 * f0; s1 += f1; s21 += f1 * f1;
    unsigned pk = (unsigned)a0 | ((unsigned)a1 << 16);
    *(unsigned*)(hT + ((unsigned long)b * HW + hw0 + hw) * Cn + c0 + 2 * cp) = pk;
  }
  red[(2 * cp) * 17 + sub * 2]     = s0;
  red[(2 * cp) * 17 + sub * 2 + 1] = s20;
  red[(2 * cp + 1) * 17 + sub * 2]     = s1;
  red[(2 * cp + 1) * 17 + sub * 2 + 1] = s21;
  __syncthreads();
  if (tid < 64) {
    float a = 0.f, q = 0.f;
#pragma unroll
    for (int j = 0; j < 8; ++j) { a += red[tid * 17 + j * 2]; q += red[tid * 17 + j * 2 + 1]; }
    float* pp = part + (((unsigned long)(b * Cn + c0 + tid)) * 64 + hwc) * 2;
    pp[0] = a; pp[1] = q;
  }
}

// ---------------- kernel 6: finalize stats -> scale/shift --------------------
__global__ void k_fin(const float* __restrict__ part, const float* __restrict__ inw,
                      const float* __restrict__ inb, float* __restrict__ ss) {
  int id = blockIdx.x * 256 + threadIdx.x;  // 4096 = B*C
  int c = id & 255;
  float s = 0.f, s2 = 0.f;
  const float* pp = part + (unsigned long)id * 128;
  for (int j = 0; j < 64; ++j) { s += pp[2 * j]; s2 += pp[2 * j + 1]; }
  float mean = s * (1.0f / HW);
  float var = s2 * (1.0f / HW) - mean * mean;
  float rs = rsqrtf(var + 1e-5f);
  float scv = rs * inw[c];
  float sh = inb[c] - mean * scv;
  ss[id * 2] = scv; ss[id * 2 + 1] = sh;
}

// ---------------- kernel 7: persistent fused GEMM + epilogue -----------------
// R6 structure + (a) store-aware counted vmcnt (stores NEVER drained mid-loop:
// wait N = issue-order distance to the needed B chunk; 36 = 32 stores + 1
// stage at s==3), (b) h16 LDS snapshot at chunk s==g replaces global f32
// h reads in the epilogue (snapshot ds_reads are pinned by the lgkmcnt(0)
// guard before the release barrier).
__global__ __launch_bounds__(512, 1) void k_main(
    const unsigned short* __restrict__ hT, const unsigned short* __restrict__ Gt,
    const float* __restrict__ bv, const float* __restrict__ ss,
    float* __restrict__ out) {
  int x = blockIdx.x;
  int o = x & 7, idx = x >> 3;
  int b = idx >> 2, g = idx & 3;
  int tid = threadIdx.x;
  int w = tid >> 6, lane = tid & 63;
  int mw = w >> 2, nw = w & 3;
  int lr = lane & 15, lg = lane >> 4;

  __shared__ __align__(16) unsigned char Ab[65536];
  __shared__ __align__(16) unsigned char Bb[2][32768];

  const char* Gblob = (const char*)Gt + (unsigned long)(b * 4 + g) * 65536;
  const char* hTb = (const char*)hT + (unsigned long)b * HW * 512;  // plain rows

  // stage A once: linear copy of pre-swizzled image (wave-uniform dest)
#pragma unroll
  for (int i = 0; i < 8; ++i)
    gl_lds16(Gblob + i * 8192 + w * 1024 + lane * 16, &Ab[i * 8192 + w * 1024]);

  // B chunk c2 = t*4+s: hw rows (o*8+t)*256..+256, channels s*64..+64.
  // LDS image swizzled: Bb[row*128+cb] = hTplain[row][s*128 + (cb^((row&7)<<4))]
#define STAGE_B(c2, buf_)                                                        \
  {                                                                              \
    int s2_ = (c2) & 3, t2_ = (c2) >> 2;                                         \
    const char* base_ = hTb + (unsigned long)((o * 8 + t2_) * 256) * 512 + s2_ * 128; \
    _Pragma("unroll")                                                            \
    for (int l_ = 0; l_ < 4; ++l_) {                                             \
      int rowl_ = l_ * 64 + w * 8 + (lane >> 3);                                 \
      int bir_ = ((lane & 7) * 16) ^ ((rowl_ & 7) << 4);                         \
      gl_lds16(base_ + (unsigned long)rowl_ * 512 + bir_,                        \
               &Bb[buf_][l_ * 8192 + w * 1024]);                                 \
    }                                                                            \
  }

  f32x4 acc[4][4];
#pragma unroll
  for (int mf = 0; mf < 4; ++mf)
#pragma unroll
    for (int nf = 0; nf < 4; ++nf) acc[mf][nf] = (f32x4){0.f, 0.f, 0.f, 0.f};

  unsigned short h16[2][4][4];
  const float* ssb = ss + b * Cn * 2;
  const float* bvb = bv + b * 512 + g * 128;

  STAGE_B(0, 0);
  STAGE_B(1, 1);
  asm volatile("s_waitcnt vmcnt(4)" ::: "memory");  // A + chunk0 done (B1 pending)
  __builtin_amdgcn_s_barrier();
  __builtin_amdgcn_sched_barrier(0);

// compute chunk ch_ (s-slot s_) from Bb[ch_&1]; snapshot h16 when s_==g
#define COMPUTE(ch_, s_)                                                         \
  {                                                                              \
    const unsigned char* Bcur = &Bb[(ch_) & 1][0];                               \
    if ((s_) == g) {                                                             \
      _Pragma("unroll") for (int p = 0; p < 2; ++p)                              \
      _Pragma("unroll") for (int nf = 0; nf < 4; ++nf) {                         \
        int row = nw * 64 + nf * 16 + lr;                                        \
        int sw = (row & 7) << 4;                                                 \
        _Pragma("unroll") for (int r = 0; r < 4; ++r) {                          \
          int c_loc = (mw * 2 + p) * 16 + lg * 4 + r;                            \
          h16[p][nf][r] = *(const unsigned short*)(&Bcur[row * 128 + ((c_loc * 2) ^ sw)]); \
        }                                                                        \
      }                                                                          \
    }                                                                            \
    _Pragma("unroll") for (int kk = 0; kk < 2; ++kk) {                           \
      short8 afr[4], bfr[4];                                                     \
      _Pragma("unroll") for (int mf = 0; mf < 4; ++mf) {                         \
        int row = mw * 64 + mf * 16 + lr;                                        \
        afr[mf] = *(const short8*)(                                              \
            &Ab[row * 512 + (((s_) * 128 + kk * 64 + lg * 16) ^ ((row & 7) << 4))]); \
      }                                                                          \
      _Pragma("unroll") for (int nf = 0; nf < 4; ++nf) {                         \
        int row = nw * 64 + nf * 16 + lr;                                        \
        bfr[nf] = *(const short8*)(                                              \
            &Bcur[row * 128 + ((kk * 64 + lg * 16) ^ ((row & 7) << 4))]);        \
      }                                                                          \
      _Pragma("unroll") for (int mf = 0; mf < 4; ++mf)                           \
        _Pragma("unroll") for (int nf = 0; nf < 4; ++nf)                         \
          acc[mf][nf] = __builtin_amdgcn_mfma_f32_16x16x32_bf16(afr[mf], bfr[nf], \
                                                                acc[mf][nf], 0, 0, 0); \
    }                                                                            \
  }

#define EPILOGUE(t_)                                                             \
  {                                                                              \
    int hwbase = (o * 8 + (t_)) * 256 + nw * 64 + lr;                            \
    _Pragma("unroll") for (int p = 0; p < 2; ++p)                                \
    _Pragma("unroll") for (int r = 0; r < 4; ++r) {                              \
      int c_loc = (mw * 2 + p) * 16 + lg * 4 + r;                                \
      int cch = g * 64 + c_loc;                                                  \
      float scv = ssb[cch * 2], sh = ssb[cch * 2 + 1];                           \
      float bvg = bvb[c_loc], bvbt = bvb[64 + c_loc];                            \
      float* orow = out + (unsigned long)(b * Cn + cch) * HW + hwbase;           \
      _Pragma("unroll") for (int nf = 0; nf < 4; ++nf) {                         \
        float hn = bf2f(h16[p][nf][r]) * scv + sh;                               \
        orow[nf * 16] = hn * (acc[2 * p][nf][r] + bvg) + (acc[2 * p + 1][nf][r] + bvbt); \
      }                                                                          \
    }                                                                            \
    _Pragma("unroll") for (int mf = 0; mf < 4; ++mf)                             \
      _Pragma("unroll") for (int nf = 0; nf < 4; ++nf)                           \
        acc[mf][nf] = (f32x4){0.f, 0.f, 0.f, 0.f};                               \
  }

// release buf ch_&1, stage chunk ch_+2 into it, counted-wait VM_ for chunk
// ch_+1 (VM_ = #vmcnt-ops issued after B(ch_+1): 4 normally, 36 after an
// epilogue's 32 stores), acquire.
#define SYNC_STAGE(ch_, VM_)                                                     \
  asm volatile("s_waitcnt lgkmcnt(0)" ::: "memory");                             \
  __builtin_amdgcn_sched_barrier(0);                                             \
  __builtin_amdgcn_s_barrier();                                                  \
  STAGE_B((ch_) + 2, (ch_) & 1);                                                 \
  asm volatile("s_waitcnt vmcnt(" #VM_ ")" ::: "memory");                        \
  __builtin_amdgcn_s_barrier();                                                  \
  __builtin_amdgcn_sched_barrier(0);

  // t = 0
  COMPUTE(0, 0) SYNC_STAGE(0, 4)
  COMPUTE(1, 1) SYNC_STAGE(1, 4)
  COMPUTE(2, 2) SYNC_STAGE(2, 4)
  COMPUTE(3, 3) EPILOGUE(0) SYNC_STAGE(3, 36)
  // t = 1..6
  for (int t = 1; t < 7; ++t) {
    int ch = t * 4;
    COMPUTE(ch, 0) SYNC_STAGE(ch, 4)
    COMPUTE(ch + 1, 1) SYNC_STAGE(ch + 1, 4)
    COMPUTE(ch + 2, 2) SYNC_STAGE(ch + 2, 4)
    COMPUTE(ch + 3, 3) EPILOGUE(t) SYNC_STAGE(ch + 3, 36)
  }
  // t = 7 (tail: B31 staged at ch=29; ch=30 stages nothing)
  COMPUTE(28, 0) SYNC_STAGE(28, 4)
  COMPUTE(29, 1) SYNC_STAGE(29, 4)
  COMPUTE(30, 2)
  asm volatile("s_waitcnt lgkmcnt(0)" ::: "memory");
  __builtin_amdgcn_sched_barrier(0);
  __builtin_amdgcn_s_barrier();
  asm volatile("s_waitcnt vmcnt(0)" ::: "memory");
  __builtin_amdgcn_s_barrier();
  __builtin_amdgcn_sched_barrier(0);
  COMPUTE(31, 3) EPILOGUE(7)

#undef SYNC_STAGE
#undef EPILOGUE
#undef COMPUTE
#undef STAGE_B
}

__global__ void k_sentinel(float* out) { out[0] = 12345.0f; }

// ---------------- launcher ---------------------------------------------------
extern "C" void kernel_launch(void* const* d_in, const int* in_sizes, int n_in,
                              void* d_out, int out_size, void* d_ws, size_t ws_size,
                              hipStream_t stream) {
  const float* wsrc   = (const float*)d_in[0];
  const float* wtgt   = (const float*)d_in[1];
  const float* h      = (const float*)d_in[2];
  const float* conv0w = (const float*)d_in[3];
  const float* conv0b = (const float*)d_in[4];
  const float* fckw   = (const float*)d_in[5];
  const float* fckb   = (const float*)d_in[6];
  const float* fcw    = (const float*)d_in[7];
  const float* fcb    = (const float*)d_in[8];
  const float* inw    = (const float*)d_in[9];
  const float* inb    = (const float*)d_in[10];
  float* out = (float*)d_out;
  char* ws = (char*)d_ws;

  const size_t NEED = 142542848ull;
  if (ws_size < NEED) {
    k_sentinel<<<1, 1, 0, stream>>>(out);
    return;
  }

  unsigned short* hT = (unsigned short*)(ws + 0);           // 134217728
  float* kmat   = (float*)(ws + 134217728);                 // 393216
  float* walloc = (float*)(ws + 134610944);                 // 393216
  float* bias0  = (float*)(ws + 135004160);                 // 2048
  float* bg     = (float*)(ws + 135006208);                 // 786432
  float* Mmat   = (float*)(ws + 135792640);                 // 393216
  unsigned short* Gt = (unsigned short*)(ws + 136185856);   // 4194304
  float* bv     = (float*)(ws + 140380160);                 // 32768
  float* part   = (float*)(ws + 140412928);                 // 2097152
  float* ss     = (float*)(ws + 142510080);                 // 32768

  dim3 gt(64, 4, Bn);
  k_tr<<<gt, 256, 0, stream>>>(h, hT, part);
  k_keys<<<Bn * Ln, 256, 0, stream>>>(wsrc, fckw, fckb, kmat);
  k_alloc<<<Bn, 256, 0, stream>>>(wsrc, wtgt, conv0b, kmat, walloc, bias0);
  k_mbg<<<2 * Bn * Ln, 256, 0, stream>>>(kmat, conv0w, walloc, fcw, fcb, Mmat, bg);
  dim3 gg(4, Bn);
  k_gbuild<<<gg, 256, 0, stream>>>(Mmat, bg, bias0, Gt, bv);
  k_fin<<<16, 256, 0, stream>>>(part, inw, inb, ss);
  k_main<<<512, 512, 0, stream>>>(hT, Gt, bv, ss, out);
}

// Round 8
// 346.371 us; speedup vs baseline: 1.1118x; 1.0072x over previous
//
#include <hip/hip_runtime.h>
#include <stdint.h>

#define HW 16384
#define Bn 16
#define Ln 24
#define Dn 256
#define Qn 256
#define Cn 256

typedef __attribute__((ext_vector_type(8))) short short8;
typedef __attribute__((ext_vector_type(4))) float f32x4;

__device__ __forceinline__ unsigned short f2bf(float f) {
  unsigned u = __builtin_bit_cast(unsigned, f);
  u += 0x7FFFu + ((u >> 16) & 1u);
  return (unsigned short)(u >> 16);
}
__device__ __forceinline__ float bf2f(unsigned short s) {
  return __builtin_bit_cast(float, (unsigned)s << 16);
}

__device__ __forceinline__ void gl_lds16(const void* gsrc, void* lds) {
  __builtin_amdgcn_global_load_lds(
      (const __attribute__((address_space(1))) unsigned int*)gsrc,
      (__attribute__((address_space(3))) unsigned int*)lds, 16, 0, 0);
}

// ---------------- kernel 1: k[b,l,q] = w_src[b,l,:]·fck_w[q,:] + fck_b[q] ----
__global__ void k_keys(const float* __restrict__ wsrc, const float* __restrict__ fckw,
                       const float* __restrict__ fckb, float* __restrict__ kmat) {
  int b = blockIdx.x / Ln, l = blockIdx.x % Ln;
  __shared__ float row[Dn];
  row[threadIdx.x] = wsrc[(b * Ln + l) * Dn + threadIdx.x];
  __syncthreads();
  int q = threadIdx.x;
  const float* wq = fckw + q * Dn;
  float acc = fckb[q];
#pragma unroll 8
  for (int d = 0; d < Dn; ++d) acc += row[d] * wq[d];
  kmat[(b * Ln + l) * Qn + q] = acc;
}

// ---------------- kernel 2: scores/argmax/w_alloc/bias0 ----------------------
__global__ void k_alloc(const float* __restrict__ wsrc, const float* __restrict__ wtgt,
                        const float* __restrict__ conv0b, const float* __restrict__ kmat,
                        float* __restrict__ walloc, float* __restrict__ bias0) {
  int b = blockIdx.x;
  __shared__ float S[Ln][Dn];
  __shared__ float T[Ln][Dn];
  __shared__ double sc[Ln][Ln];
  __shared__ double cs[Ln];
  __shared__ int idx[Ln];
  int tid = threadIdx.x;
  for (int n = tid; n < Ln * Dn; n += 256) {
    S[n >> 8][n & 255] = wsrc[b * Ln * Dn + n];
    T[n >> 8][n & 255] = wtgt[b * Ln * Dn + n];
  }
  __syncthreads();
  for (int p = tid; p < Ln * Ln; p += 256) {
    int l = p / Ln, m = p % Ln;
    double a = 0.0;
    for (int d = 0; d < Dn; ++d) a += (double)S[l][d] * (double)T[m][d];
    sc[l][m] = a;
  }
  __syncthreads();
  if (tid < Ln) {
    double a = 0.0;
    for (int l = 0; l < Ln; ++l) a += sc[l][tid];
    cs[tid] = a;
  }
  __syncthreads();
  if (tid < Ln) {
    double best = -1e300; int bi = 0;
    for (int m = 0; m < Ln; ++m) {
      double v = cs[m] - sc[tid][m];
      if (v > best) { best = v; bi = m; }
    }
    idx[tid] = bi;
  }
  __syncthreads();
  for (int n = tid; n < Ln * Dn; n += 256) {
    int l = n >> 8, d = n & 255;
    walloc[b * Ln * Dn + n] = T[idx[l]][d];
  }
  if (tid < Ln) {
    float a = 0.f;
    const float* kr = kmat + (b * Ln + tid) * Qn;
    for (int q = 0; q < Qn; ++q) a += conv0b[q] * kr[q];
    bias0[b * Ln + tid] = a;
  }
}

// ---------------- kernel 3: M[b,l,c] and bg[b,l,e] ---------------------------
__global__ void k_mbg(const float* __restrict__ kmat, const float* __restrict__ conv0w,
                      const float* __restrict__ walloc, const float* __restrict__ fcw,
                      const float* __restrict__ fcb,
                      float* __restrict__ Mmat, float* __restrict__ bg) {
  int bid = blockIdx.x;
  __shared__ float row[Dn];
  if (bid < Bn * Ln) {
    int b = bid / Ln, l = bid % Ln;
    row[threadIdx.x] = kmat[(b * Ln + l) * Qn + threadIdx.x];
    __syncthreads();
    int c = threadIdx.x;
    float acc = 0.f;
    for (int q = 0; q < Qn; ++q) acc += row[q] * conv0w[q * Cn + c];
    Mmat[(b * Ln + l) * Cn + c] = acc;
  } else {
    int id = bid - Bn * Ln;
    int b = id / Ln, l = id % Ln;
    row[threadIdx.x] = walloc[(b * Ln + l) * Dn + threadIdx.x];
    __syncthreads();
    for (int it = 0; it < 2; ++it) {
      int e = it * 256 + threadIdx.x;
      const float* we = fcw + e * Dn;
      float acc = fcb[e];
      for (int d = 0; d < Dn; ++d) acc += row[d] * we[d];
      bg[(b * Ln + l) * (2 * Cn) + e] = acc;
    }
  }
}

// ---------------- kernel 4: G blob per (b,g): pre-swizzled image + bv --------
// R2/R6/R7-VALIDATED image. 128 rows x 512B (k=256 bf16). Row r: isb=(r>>4)&1,
// c_loc = (r>>5)*16 + (r&15). gamma rows isb=0 (bg col 256+c), beta isb=1.
// byte(r,k) = r*512 + (k*2 ^ ((r&7)<<4)).
__global__ void k_gbuild(const float* __restrict__ Mmat, const float* __restrict__ bg,
                         const float* __restrict__ bias0,
                         unsigned short* __restrict__ Gt, float* __restrict__ bv) {
  int g = blockIdx.x, b = blockIdx.y;
  __shared__ float Ms[Ln][Dn];
  __shared__ float Gb[Ln][128];
  __shared__ float B0[Ln];
  int tid = threadIdx.x;
  for (int n = tid; n < Ln * Dn; n += 256) Ms[n >> 8][n & 255] = Mmat[b * Ln * Dn + n];
  for (int n = tid; n < Ln * 128; n += 256) {
    int l = n >> 7, j = n & 127;
    int e = (j < 64) ? (Cn + g * 64 + j) : (g * 64 + (j - 64));
    Gb[l][j] = bg[(b * Ln + l) * (2 * Cn) + e];
  }
  if (tid < Ln) B0[tid] = bias0[b * Ln + tid];
  __syncthreads();
  char* base = (char*)Gt + (unsigned long)(b * 4 + g) * 65536;
  for (int r = 0; r < 128; ++r) {
    int isb = (r >> 4) & 1;
    int c_loc = (r >> 5) * 16 + (r & 15);
    int j = c_loc + isb * 64;
    float acc = 0.f;
#pragma unroll
    for (int l = 0; l < Ln; ++l) acc += Ms[l][tid] * Gb[l][j];
    unsigned off = (unsigned)((r * 512 + tid * 2) ^ ((r & 7) << 4));
    *(unsigned short*)(base + off) = f2bf(acc);
  }
  if (tid < 128) {
    float a = 0.f;
#pragma unroll
    for (int l = 0; l < Ln; ++l) a += B0[l] * Gb[l][tid];
    bv[b * 512 + g * 128 + tid] = a;  // 0..63 gamma-bias, 64..127 beta-bias
  }
}

// ---------------- kernel 5: transpose h -> hT (PLAIN [b][hw][c] bf16) + stats
// R1/R6/R7-VALIDATED verbatim.
__global__ void k_tr(const float* __restrict__ h, unsigned short* __restrict__ hT,
                     float* __restrict__ part) {
  int hwc = blockIdx.x;  // 64 chunks of 256 hw
  int cc  = blockIdx.y;  // 4 chunks of 64 c
  int b   = blockIdx.z;
  int tid = threadIdx.x;
  int w = tid >> 6, lane = tid & 63;
  __shared__ unsigned short tile[64 * 258];
  __shared__ float red[64 * 17 + 16];
  const int c0 = cc * 64, hw0 = hwc * 256;
  for (int i = 0; i < 16; ++i) {
    int cl = i * 4 + w;
    f32x4 v = *(const f32x4*)(h + ((unsigned long)(b * Cn + c0 + cl)) * HW + hw0 + lane * 4);
    unsigned lo = (unsigned)f2bf(v.x) | ((unsigned)f2bf(v.y) << 16);
    unsigned hi = (unsigned)f2bf(v.z) | ((unsigned)f2bf(v.w) << 16);
    unsigned* dst = (unsigned*)(tile + cl * 258 + lane * 4);
    dst[0] = lo; dst[1] = hi;
  }
  __syncthreads();
  int cp = tid & 31, sub = tid >> 5;
  float s0 = 0.f, s20 = 0.f, s1 = 0.f, s21 = 0.f;
  for (int i = 0; i < 32; ++i) {
    int hw = i * 8 + sub;
    unsigned short a0 = tile[(2 * cp) * 258 + hw];
    unsigned short a1 = tile[(2 * cp + 1) * 258 + hw];
    float f0 = bf2f(a0), f1 = bf2f(a1);
    s0 += f0; s20 += f0 * f0; s1 += f1; s21 += f1 * f1;
    unsigned pk = (unsigned)a0 | ((unsigned)a1 << 16);
    *(unsigned*)(hT + ((unsigned long)b * HW + hw0 + hw) * Cn + c0 + 2 * cp) = pk;
  }
  red[(2 * cp) * 17 + sub * 2]     = s0;
  red[(2 * cp) * 17 + sub * 2 + 1] = s20;
  red[(2 * cp + 1) * 17 + sub * 2]     = s1;
  red[(2 * cp + 1) * 17 + sub * 2 + 1] = s21;
  __syncthreads();
  if (tid < 64) {
    float a = 0.f, q = 0.f;
#pragma unroll
    for (int j = 0; j < 8; ++j) { a += red[tid * 17 + j * 2]; q += red[tid * 17 + j * 2 + 1]; }
    float* pp = part + (((unsigned long)(b * Cn + c0 + tid)) * 64 + hwc) * 2;
    pp[0] = a; pp[1] = q;
  }
}

// ---------------- kernel 6: finalize stats -> scale/shift --------------------
__global__ void k_fin(const float* __restrict__ part, const float* __restrict__ inw,
                      const float* __restrict__ inb, float* __restrict__ ss) {
  int id = blockIdx.x * 256 + threadIdx.x;  // 4096 = B*C
  int c = id & 255;
  float s = 0.f, s2 = 0.f;
  const float* pp = part + (unsigned long)id * 128;
  for (int j = 0; j < 64; ++j) { s += pp[2 * j]; s2 += pp[2 * j + 1]; }
  float mean = s * (1.0f / HW);
  float var = s2 * (1.0f / HW) - mean * mean;
  float rs = rsqrtf(var + 1e-5f);
  float scv = rs * inw[c];
  float sh = inb[c] - mean * scv;
  ss[id * 2] = scv; ss[id * 2 + 1] = sh;
}

// ---------------- kernel 7: persistent fused GEMM + epilogue -----------------
// R7 structure deepened: B in 16KB half-chunks (256hw x 32ch, one kk), FOUR
// buffers -> prefetch depth 3 (stage ch+4 has ~3 compute phases of cover).
// Counted waits: N=6 steady, 38 around epilogue stores (never drained),
// exact 4/2/0 tail. B quad-swizzle (quad ^= (row>>1)&3) folded into the
// per-lane GLOBAL source; LDS dest stays wave-uniform + lane*16 (rule m104).
__global__ __launch_bounds__(512, 1) void k_main(
    const unsigned short* __restrict__ hT, const unsigned short* __restrict__ Gt,
    const float* __restrict__ bv, const float* __restrict__ ss,
    float* __restrict__ out) {
  int x = blockIdx.x;
  int o = x & 7, idx = x >> 3;
  int b = idx >> 2, g = idx & 3;
  int tid = threadIdx.x;
  int w = tid >> 6, lane = tid & 63;
  int mw = w >> 2, nw = w & 3;
  int lr = lane & 15, lg = lane >> 4;

  __shared__ __align__(16) unsigned char Ab[65536];
  __shared__ __align__(16) unsigned char Bb[4][16384];

  const char* Gblob = (const char*)Gt + (unsigned long)(b * 4 + g) * 65536;
  const char* hTb = (const char*)hT + (unsigned long)b * HW * 512;  // plain rows

  // stage A once: linear copy of pre-swizzled image (wave-uniform dest)
#pragma unroll
  for (int i = 0; i < 8; ++i)
    gl_lds16(Gblob + i * 8192 + w * 1024 + lane * 16, &Ab[i * 8192 + w * 1024]);

  // B half-chunk ch = t*8+s: hw rows (o*8+t)*256..+256, channels s*32..+32.
  // LDS image: Bb[row*64 + q*16 + u] = hTplain[row][s*64 + (q^((row>>1)&3))*16 + u]
#define STAGE_B(c2, buf_)                                                        \
  {                                                                              \
    int s2_ = (c2) & 7, t2_ = (c2) >> 3;                                         \
    const char* base_ = hTb + (unsigned long)((o * 8 + t2_) * 256) * 512;        \
    _Pragma("unroll")                                                            \
    for (int l_ = 0; l_ < 2; ++l_) {                                             \
      int rowg_ = l_ * 128 + w * 16 + (lane >> 2);                               \
      int bir_ = s2_ * 64 + ((((lane & 3) << 4)) ^ (((rowg_ >> 1) & 3) << 4));   \
      gl_lds16(base_ + (unsigned long)rowg_ * 512 + bir_,                        \
               &Bb[buf_][l_ * 8192 + w * 1024]);                                 \
    }                                                                            \
  }

  f32x4 acc[4][4];
#pragma unroll
  for (int mf = 0; mf < 4; ++mf)
#pragma unroll
    for (int nf = 0; nf < 4; ++nf) acc[mf][nf] = (f32x4){0.f, 0.f, 0.f, 0.f};

  unsigned short h16[2][4][4];
  const float* ssb = ss + b * Cn * 2;
  const float* bvb = bv + b * 512 + g * 128;
  const int ssnap = 2 * g + mw;  // per-wave uniform snapshot half-chunk

  STAGE_B(0, 0);
  STAGE_B(1, 1);
  STAGE_B(2, 2);
  STAGE_B(3, 3);
  asm volatile("s_waitcnt vmcnt(6)" ::: "memory");  // A + B0 done (B1..B3 pending)
  __builtin_amdgcn_s_barrier();
  __builtin_amdgcn_sched_barrier(0);

// compute half-chunk ch_ (s-slot s_, one kk) from Bb[ch_&3]
#define COMPUTE(ch_, s_)                                                         \
  {                                                                              \
    const unsigned char* Bcur = &Bb[(ch_) & 3][0];                               \
    if ((s_) == ssnap) {                                                         \
      _Pragma("unroll") for (int p = 0; p < 2; ++p)                              \
      _Pragma("unroll") for (int nf = 0; nf < 4; ++nf) {                         \
        int row = nw * 64 + nf * 16 + lr;                                        \
        int sw = ((row >> 1) & 3) << 4;                                          \
        _Pragma("unroll") for (int r = 0; r < 4; ++r) {                          \
          int kloc = p * 16 + lg * 4 + r;                                        \
          h16[p][nf][r] = *(const unsigned short*)(&Bcur[row * 64 + ((kloc * 2) ^ sw)]); \
        }                                                                        \
      }                                                                          \
    }                                                                            \
    short8 afr[4], bfr[4];                                                       \
    _Pragma("unroll") for (int mf = 0; mf < 4; ++mf) {                           \
      int row = mw * 64 + mf * 16 + lr;                                          \
      afr[mf] = *(const short8*)(                                                \
          &Ab[row * 512 + (((s_) * 64 + lg * 16) ^ ((row & 7) << 4))]);          \
    }                                                                            \
    _Pragma("unroll") for (int nf = 0; nf < 4; ++nf) {                           \
      int row = nw * 64 + nf * 16 + lr;                                          \
      bfr[nf] = *(const short8*)(                                                \
          &Bcur[row * 64 + ((lg << 4) ^ (((row >> 1) & 3) << 4))]);              \
    }                                                                            \
    _Pragma("unroll") for (int mf = 0; mf < 4; ++mf)                             \
      _Pragma("unroll") for (int nf = 0; nf < 4; ++nf)                           \
        acc[mf][nf] = __builtin_amdgcn_mfma_f32_16x16x32_bf16(afr[mf], bfr[nf],  \
                                                              acc[mf][nf], 0, 0, 0); \
  }

#define EPILOGUE(t_)                                                             \
  {                                                                              \
    int hwbase = (o * 8 + (t_)) * 256 + nw * 64 + lr;                            \
    _Pragma("unroll") for (int p = 0; p < 2; ++p)                                \
    _Pragma("unroll") for (int r = 0; r < 4; ++r) {                              \
      int c_loc = (mw * 2 + p) * 16 + lg * 4 + r;                                \
      int cch = g * 64 + c_loc;                                                  \
      float scv = ssb[cch * 2], sh = ssb[cch * 2 + 1];                           \
      float bvg = bvb[c_loc], bvbt = bvb[64 + c_loc];                            \
      float* orow = out + (unsigned long)(b * Cn + cch) * HW + hwbase;           \
      _Pragma("unroll") for (int nf = 0; nf < 4; ++nf) {                         \
        float hn = bf2f(h16[p][nf][r]) * scv + sh;                               \
        orow[nf * 16] = hn * (acc[2 * p][nf][r] + bvg) + (acc[2 * p + 1][nf][r] + bvbt); \
      }                                                                          \
    }                                                                            \
    _Pragma("unroll") for (int mf = 0; mf < 4; ++mf)                             \
      _Pragma("unroll") for (int nf = 0; nf < 4; ++nf)                           \
        acc[mf][nf] = (f32x4){0.f, 0.f, 0.f, 0.f};                               \
  }

// release buf ch_&3, stage ch_+4 into it, counted-wait N_ for chunk ch_+1
#define SYNCS(ch_, N_)                                                           \
  asm volatile("s_waitcnt lgkmcnt(0)" ::: "memory");                             \
  __builtin_amdgcn_sched_barrier(0);                                             \
  __builtin_amdgcn_s_barrier();                                                  \
  STAGE_B((ch_) + 4, (ch_) & 3);                                                 \
  asm volatile("s_waitcnt vmcnt(" #N_ ")" ::: "memory");                         \
  __builtin_amdgcn_s_barrier();                                                  \
  __builtin_amdgcn_sched_barrier(0);

#define SYNCT(N_)                                                                \
  asm volatile("s_waitcnt lgkmcnt(0)" ::: "memory");                             \
  __builtin_amdgcn_sched_barrier(0);                                             \
  __builtin_amdgcn_s_barrier();                                                  \
  asm volatile("s_waitcnt vmcnt(" #N_ ")" ::: "memory");                         \
  __builtin_amdgcn_s_barrier();                                                  \
  __builtin_amdgcn_sched_barrier(0);

  for (int t = 0; t < 7; ++t) {
    int c0 = t * 8;
    COMPUTE(c0 + 0, 0) SYNCS(c0 + 0, 38)
    COMPUTE(c0 + 1, 1) SYNCS(c0 + 1, 38)
    COMPUTE(c0 + 2, 2) SYNCS(c0 + 2, 6)
    COMPUTE(c0 + 3, 3) SYNCS(c0 + 3, 6)
    COMPUTE(c0 + 4, 4) SYNCS(c0 + 4, 6)
    COMPUTE(c0 + 5, 5) SYNCS(c0 + 5, 6)
    COMPUTE(c0 + 6, 6) SYNCS(c0 + 6, 6)
    COMPUTE(c0 + 7, 7) EPILOGUE(t) SYNCS(c0 + 7, 38)
  }
  // t = 7 tail (B60..B63 staged at syncs 56..59; exact waits thereafter)
  COMPUTE(56, 0) SYNCS(56, 38)
  COMPUTE(57, 1) SYNCS(57, 38)
  COMPUTE(58, 2) SYNCS(58, 6)
  COMPUTE(59, 3) SYNCS(59, 6)
  COMPUTE(60, 4) SYNCT(4)
  COMPUTE(61, 5) SYNCT(2)
  COMPUTE(62, 6) SYNCT(0)
  COMPUTE(63, 7) EPILOGUE(7)

#undef SYNCT
#undef SYNCS
#undef EPILOGUE
#undef COMPUTE
#undef STAGE_B
}

__global__ void k_sentinel(float* out) { out[0] = 12345.0f; }

// ---------------- launcher ---------------------------------------------------
extern "C" void kernel_launch(void* const* d_in, const int* in_sizes, int n_in,
                              void* d_out, int out_size, void* d_ws, size_t ws_size,
                              hipStream_t stream) {
  const float* wsrc   = (const float*)d_in[0];
  const float* wtgt   = (const float*)d_in[1];
  const float* h      = (const float*)d_in[2];
  const float* conv0w = (const float*)d_in[3];
  const float* conv0b = (const float*)d_in[4];
  const float* fckw   = (const float*)d_in[5];
  const float* fckb   = (const float*)d_in[6];
  const float* fcw    = (const float*)d_in[7];
  const float* fcb    = (const float*)d_in[8];
  const float* inw    = (const float*)d_in[9];
  const float* inb    = (const float*)d_in[10];
  float* out = (float*)d_out;
  char* ws = (char*)d_ws;

  const size_t NEED = 142542848ull;
  if (ws_size < NEED) {
    k_sentinel<<<1, 1, 0, stream>>>(out);
    return;
  }

  unsigned short* hT = (unsigned short*)(ws + 0);           // 134217728
  float* kmat   = (float*)(ws + 134217728);                 // 393216
  float* walloc = (float*)(ws + 134610944);                 // 393216
  float* bias0  = (float*)(ws + 135004160);                 // 2048
  float* bg     = (float*)(ws + 135006208);                 // 786432
  float* Mmat   = (float*)(ws + 135792640);                 // 393216
  unsigned short* Gt = (unsigned short*)(ws + 136185856);   // 4194304
  float* bv     = (float*)(ws + 140380160);                 // 32768
  float* part   = (float*)(ws + 140412928);                 // 2097152
  float* ss     = (float*)(ws + 142510080);                 // 32768

  dim3 gt(64, 4, Bn);
  k_tr<<<gt, 256, 0, stream>>>(h, hT, part);
  k_keys<<<Bn * Ln, 256, 0, stream>>>(wsrc, fckw, fckb, kmat);
  k_alloc<<<Bn, 256, 0, stream>>>(wsrc, wtgt, conv0b, kmat, walloc, bias0);
  k_mbg<<<2 * Bn * Ln, 256, 0, stream>>>(kmat, conv0w, walloc, fcw, fcb, Mmat, bg);
  dim3 gg(4, Bn);
  k_gbuild<<<gg, 256, 0, stream>>>(Mmat, bg, bias0, Gt, bv);
  k_fin<<<16, 256, 0, stream>>>(part, inw, inb, ss);
  k_main<<<512, 512, 0, stream>>>(hT, Gt, bv, ss, out);
}